// Round 1
// baseline (265.031 us; speedup 1.0000x reference)
//
#include <hip/hip_runtime.h>
#include <hip/hip_fp16.h>

#define NB   128
#define SPB_ 512
#define NPOS 131072   // 128*32*32
#define NBIN 256      // packed bins: plane 0 holds (bin0, bin256)

static __device__ __forceinline__ float clamp01(float v) {
    return fminf(fmaxf(v, 0.0f), 1.0f);
}

// ---------------------------------------------------------------------------
// K1: per-position H[k] = clip(tf)[k] * rfft_unnorm(env)[k], stored as f16
// layout Hbuf[k][pos], pos = b*1024 + h*32 + w.
// Block = 256 threads = 4 waves; 16 consecutive positions per block
// (4 rounds of 4 concurrent per-wave FFTs), LDS transpose for coalesced out.
// Packed real FFT: z[n] = env[2n] + i*env[2n+1], 256-pt complex DIF
// (4 pts/lane), scatter bit-reversed -> natural LDS, untangle to rfft bins.
// ---------------------------------------------------------------------------
__global__ __launch_bounds__(256) void k1_fft(
    const float* __restrict__ tf,    // [NPOS][257]
    const float* __restrict__ imp,   // [NPOS][16]
    const float* __restrict__ nz,    // [NPOS][512]
    __half2* __restrict__ Hbuf)      // [NBIN][NPOS]
{
    __shared__ float2  Zbuf[4][256];
    __shared__ float   ldsImp[256];
    __shared__ __half2 stg[16][257]; // padded: bank = (r + k) % 32

    const int tid  = threadIdx.x;
    const int wv   = tid >> 6;
    const int lane = tid & 63;
    const int pos0 = blockIdx.x << 4;

    ldsImp[tid] = imp[(size_t)pos0 * 16 + tid];
    __syncthreads();

    for (int q = 0; q < 4; ++q) {
        const int r   = (wv << 2) + q;
        const int pos = pos0 + r;

        // ----- env: lane covers samples t = 8*lane .. 8*lane+7 -----
        const float* nzp = nz + (size_t)pos * SPB_ + lane * 8;
        float4 nv0 = *(const float4*)nzp;
        float4 nv1 = *(const float4*)(nzp + 4);
        float nvv[8] = {nv0.x, nv0.y, nv0.z, nv0.w, nv1.x, nv1.y, nv1.z, nv1.w};
        float er[4], ei[4];
        #pragma unroll
        for (int u = 0; u < 8; ++u) {
            int   t = lane * 8 + u;
            float p = ((float)t - 15.5f) * (1.0f / 32.0f); // half-pixel centers
            p = fminf(fmaxf(p, 0.0f), 15.0f);              // edge clamp
            int j0 = (int)p; j0 = j0 > 14 ? 14 : j0;
            float fr = p - (float)j0;
            float a  = ldsImp[(r << 4) + j0];
            float bb = ldsImp[(r << 4) + j0 + 1];
            float e  = clamp01(fmaf(fr, bb - a, a)) * nvv[u];
            if (u & 1) ei[u >> 1] = e; else er[u >> 1] = e;
        }

        // ----- 256-pt complex DIF, cross-lane stages s=128..4 -----
        #pragma unroll
        for (int s = 128; s >= 4; s >>= 1) {
            const int   lm = s >> 2;
            const bool  rb = (lane & lm) != 0;
            const float fs = -3.14159265358979f / (float)s;
            #pragma unroll
            for (int j = 0; j < 4; ++j) {
                float ro = __shfl_xor(er[j], lm, 64);
                float io = __shfl_xor(ei[j], lm, 64);
                float sr = er[j] + ro, si = ei[j] + io;   // role a: me+other
                float dr = ro - er[j], di = io - ei[j];   // role b: other-me = a-b
                int   n  = (lane << 2) | j;
                float ang = fs * (float)(n & (s - 1));
                float sv, cv; __sincosf(ang, &sv, &cv);
                float tr = cv * dr - sv * di;
                float ti = cv * di + sv * dr;
                er[j] = rb ? tr : sr;
                ei[j] = rb ? ti : si;
            }
        }
        // ----- local stage s=2: pairs (0,2),(1,3); tw = 1, -i -----
        {
            float ar = er[0], ai = ei[0], br = er[2], bi = ei[2];
            er[0] = ar + br; ei[0] = ai + bi;
            er[2] = ar - br; ei[2] = ai - bi;
            ar = er[1]; ai = ei[1]; br = er[3]; bi = ei[3];
            er[1] = ar + br; ei[1] = ai + bi;
            float dr = ar - br, di = ai - bi;  // * (-i): (dr+idi)*(-i) = di - i*dr
            er[3] = di; ei[3] = -dr;
        }
        // ----- local stage s=1: pairs (0,1),(2,3); tw = 1 -----
        {
            float ar = er[0], ai = ei[0], br = er[1], bi = ei[1];
            er[0] = ar + br; ei[0] = ai + bi; er[1] = ar - br; ei[1] = ai - bi;
            ar = er[2]; ai = ei[2]; br = er[3]; bi = ei[3];
            er[2] = ar + br; ei[2] = ai + bi; er[3] = ar - br; ei[3] = ai - bi;
        }

        // ----- scatter bit-reversed -> natural order in LDS -----
        #pragma unroll
        for (int j = 0; j < 4; ++j) {
            int p   = (lane << 2) | j;
            int rev = __brev((unsigned)p) >> 24;
            Zbuf[wv][rev] = make_float2(er[j], ei[j]);
        }
        __syncthreads();

        // ----- untangle to rfft bins, * res, f16, stage transposed -----
        const float* tfp = tf + (size_t)pos * 257;
        #pragma unroll
        for (int m = 0; m < 4; ++m) {
            int k = lane + (m << 6);
            if (k == 0) {
                float2 z0 = Zbuf[wv][0];
                float  x0   = z0.x + z0.y;    // bin 0   (real)
                float  x256 = z0.x - z0.y;    // bin 256 (real)
                float  r0   = clamp01(tfp[0]);
                float  r256 = clamp01(tfp[256]);
                stg[r][0] = __floats2half2_rn(r0 * x0, r256 * x256);
            } else {
                float2 zk = Zbuf[wv][k];
                float2 zm = Zbuf[wv][256 - k];
                float Er =  0.5f * (zk.x + zm.x);
                float Ei =  0.5f * (zk.y - zm.y);
                float Or =  0.5f * (zk.y + zm.y);
                float Oi = -0.5f * (zk.x - zm.x);
                float ang = (-3.14159265358979f / 256.0f) * (float)k; // W512^k
                float sv, cv; __sincosf(ang, &sv, &cv);
                float Xr = Er + cv * Or - sv * Oi;
                float Xi = Ei + cv * Oi + sv * Or;
                float rk = clamp01(tfp[k]);
                stg[r][k] = __floats2half2_rn(rk * Xr, rk * Xi);
            }
        }
        __syncthreads(); // stg visible; Zbuf safe to reuse next round
    }

    // ----- coalesced write-out: for each k, 16 consecutive pos = 64B -----
    const int rr    = tid & 15;
    const int kbase = tid >> 4;
    #pragma unroll
    for (int i = 0; i < 16; ++i) {
        int k = kbase + (i << 4);
        Hbuf[(size_t)k * NPOS + pos0 + rr] = stg[rr][k];
    }
}

// ---------------------------------------------------------------------------
// K2: frequency-domain scan. Block k owns bin-plane k: 32x32 complex state.
// 128 steps: state += H_b; M[b][k] = state(16,16); state = box3(state).
// ---------------------------------------------------------------------------
__global__ __launch_bounds__(1024) void k2_scan(
    const __half2* __restrict__ Hbuf,  // [NBIN][NPOS]
    float2* __restrict__ Mbuf)         // [NB][NBIN]
{
    __shared__ float2 sfb[32][33];
    const int k   = blockIdx.x;
    const int tid = threadIdx.x;
    const int h   = tid >> 5, w = tid & 31;
    const int hm = (h == 0) ? 1 : h - 1, hp = (h == 31) ? 30 : h + 1;
    const int wm = (w == 0) ? 1 : w - 1, wp = (w == 31) ? 30 : w + 1;

    const __half2* Hp = Hbuf + (size_t)k * NPOS + tid;
    __half2 cur = Hp[0];
    float fr = 0.0f, fi = 0.0f;

    for (int b = 0; b < NB; ++b) {
        float2 hv = __half22float2(cur);
        if (b < NB - 1) cur = Hp[(size_t)(b + 1) * 1024]; // prefetch
        fr += hv.x; fi += hv.y;
        if (tid == 528) Mbuf[b * NBIN + k] = make_float2(fr, fi); // mic BEFORE box
        sfb[h][w] = make_float2(fr, fi);
        __syncthreads();
        float sr = 0.0f, si = 0.0f; float2 v;
        v = sfb[hm][wm]; sr += v.x; si += v.y;
        v = sfb[hm][w ]; sr += v.x; si += v.y;
        v = sfb[hm][wp]; sr += v.x; si += v.y;
        v = sfb[h ][wm]; sr += v.x; si += v.y;
        v = sfb[h ][w ]; sr += v.x; si += v.y;
        v = sfb[h ][wp]; sr += v.x; si += v.y;
        v = sfb[hp][wm]; sr += v.x; si += v.y;
        v = sfb[hp][w ]; sr += v.x; si += v.y;
        v = sfb[hp][wp]; sr += v.x; si += v.y;
        fr = sr * (1.0f / 9.0f); fi = si * (1.0f / 9.0f);
        __syncthreads();
    }
}

// ---------------------------------------------------------------------------
// K3: per-block-b inverse rDFT (512 samples from 257 Hermitian bins, 1/512).
// ---------------------------------------------------------------------------
__global__ __launch_bounds__(512) void k3_idft(
    const float2* __restrict__ Mbuf,
    float* __restrict__ out)
{
    __shared__ float2 lm[256];
    const int b = blockIdx.x;
    const int t = threadIdx.x;
    if (t < 256) lm[t] = Mbuf[b * NBIN + t];
    __syncthreads();
    float acc = 0.0f;
    #pragma unroll 4
    for (int k = 1; k < 256; ++k) {
        int   ph  = (k * t) & 511;
        float ang = (float)ph * (3.14159265358979f / 256.0f); // 2*pi*k*t/512
        float sv, cv; __sincosf(ang, &sv, &cv);
        float2 m = lm[k];
        acc += m.x * cv - m.y * sv;
    }
    float m0 = lm[0].x, m256 = lm[0].y;
    float r  = m0 + ((t & 1) ? -m256 : m256) + 2.0f * acc;
    out[(b << 9) + t] = r * (1.0f / 512.0f);
}

extern "C" void kernel_launch(void* const* d_in, const int* in_sizes, int n_in,
                              void* d_out, int out_size, void* d_ws, size_t ws_size,
                              hipStream_t stream)
{
    const float* tf  = (const float*)d_in[1]; // (128,32,32,257)
    const float* imp = (const float*)d_in[2]; // (128,32,32,16)
    const float* nz  = (const float*)d_in[3]; // (128,32,32,512)
    float* out = (float*)d_out;

    const size_t hbytes = (size_t)NBIN * NPOS * sizeof(__half2);      // 134.2 MB
    const size_t mbytes = (size_t)NB * NBIN * sizeof(float2);         // 256 KB
    if (ws_size < hbytes + mbytes) {
        // identifiable failure: NaN-fill output instead of faulting
        hipMemsetAsync(d_out, 0xFF, (size_t)out_size * sizeof(float), stream);
        return;
    }
    __half2* Hbuf = (__half2*)d_ws;
    float2*  Mbuf = (float2*)((char*)d_ws + hbytes);

    k1_fft<<<NPOS / 16, 256, 0, stream>>>(tf, imp, nz, Hbuf);
    k2_scan<<<NBIN, 1024, 0, stream>>>(Hbuf, Mbuf);
    k3_idft<<<NB, 512, 0, stream>>>(Mbuf, out);
}